// Round 16
// baseline (172.349 us; speedup 1.0000x reference)
//
#include <hip/hip_runtime.h>
#include <hip/hip_bf16.h>
#include <math.h>

#define NH 16
#define T_ 2048
#define B_ 2
#define D_ 1024
#define EPS 1e-6f

typedef __attribute__((ext_vector_type(8))) short bf16x8;
typedef __attribute__((ext_vector_type(4))) short bf16x4;
typedef __attribute__((ext_vector_type(4))) float f32x4;

__device__ __forceinline__ float wred_sum(float v){
  #pragma unroll
  for (int o = 32; o > 0; o >>= 1) v += __shfl_xor(v, o, 64);
  return v;
}

__device__ __forceinline__ unsigned pack_bf16(float a, float b){
  __hip_bfloat162 t = __float22bfloat162_rn(make_float2(a, b));
  unsigned r; __builtin_memcpy(&r, &t, 4); return r;
}

// Bare v_exp_f32 (2^x), UNCONDITIONAL builtin (determinism hardening R15:
// __has_builtin-guarded asm fallbacks removed — hand-written MFMA/TRANS asm
// lacks compiler-inserted hazard wait-states, the prime suspect for the
// intermittent tripwire divergence).
__device__ __forceinline__ float fexp2(float x){
  return __builtin_amdgcn_exp2f(x);
}

__device__ __forceinline__ void gload_lds16(const void* g, void* l){
  __builtin_amdgcn_global_load_lds((const __attribute__((address_space(1))) void*)g,
                                   (__attribute__((address_space(3))) void*)l, 16, 0, 0);
}

// ---- convert x + weights to bf16; Wkvb rows PERMUTED: [h*48+d | 768+h*64+dv] ----
__global__ __launch_bounds__(256)
void cvt5(const float* __restrict__ x, const float* __restrict__ wq,
          const float* __restrict__ wkva, const float* __restrict__ wkvb,
          const float* __restrict__ wo,
          __hip_bfloat16* __restrict__ xb, __hip_bfloat16* __restrict__ wqb,
          __hip_bfloat16* __restrict__ wkvab, __hip_bfloat16* __restrict__ wkvbb,
          __hip_bfloat16* __restrict__ wob)
{
  const int i = blockIdx.x * 256 + threadIdx.x;     // float4 index, 1,667,072 total
  const float* s; __hip_bfloat16* d; size_t soff, doff;
  if      (i < 1048576) { s = x;    d = xb;    soff = doff = i; }
  else if (i < 1310720) { s = wq;   d = wqb;   soff = doff = i - 1048576; }
  else if (i < 1347584) { s = wkva; d = wkvab; soff = doff = i - 1310720; }
  else if (i < 1404928) {
    const int off = i - 1347584;                    // float4 idx into 1792x128
    const int srow = off >> 5, c4 = off & 31;
    const int h = srow / 112, dd = srow % 112;
    const int drow = (dd < 48) ? (h*48 + dd) : (768 + h*64 + (dd - 48));
    s = wkvb; d = wkvbb; soff = off; doff = (size_t)drow*32 + c4;
  }
  else                  { s = wo;   d = wob;   soff = doff = i - 1404928; }
  float4 v = *(const float4*)(s + soff * 4);
  *(__hip_bfloat162*)(d + doff * 4)     = __float22bfloat162_rn(make_float2(v.x, v.y));
  *(__hip_bfloat162*)(d + doff * 4 + 2) = __float22bfloat162_rn(make_float2(v.z, v.w));
}

// ---- bf16 MFMA GEMM, 128x64 tile, DOUBLE-BUFFERED staging (48KB LDS) ----
// NOTE: __launch_bounds__(256,3) tried in R12 — FAILED correctness.
// Do not retry without kernel-resource-usage + disasm evidence.
template<typename CT>
__global__ __launch_bounds__(256, 2)
void gemm_bt64(const __hip_bfloat16* __restrict__ A, const __hip_bfloat16* __restrict__ W,
               CT* __restrict__ C, int M, int N, int K)
{
  __shared__ __hip_bfloat16 As[2][128 * 64];   // 32 KB
  __shared__ __hip_bfloat16 Ws[2][64 * 64];    // 16 KB
  const int tid = threadIdx.x;
  const int wv = tid >> 6, lane = tid & 63;
  const int m = lane & 15, quad = lane >> 4;
  const int bm = blockIdx.y * 128, bn = blockIdx.x * 64;

  const __hip_bfloat16* ga[4];
  const __hip_bfloat16* gw[2];
  #pragma unroll
  for (int i = 0; i < 4; i++) {
    const int slot = i*256 + tid;
    const int row = slot >> 3, cb = slot & 7;
    ga[i] = A + (size_t)(bm + row) * K + ((cb ^ (row & 7)) << 3);
  }
  #pragma unroll
  for (int i = 0; i < 2; i++) {
    const int slot = i*256 + tid;
    const int row = slot >> 3, cb = slot & 7;
    int wr = bn + row; if (wr >= N) wr = N - 1;
    gw[i] = W + (size_t)wr * K + ((cb ^ (row & 7)) << 3);
  }
  auto stage = [&](int buf){
    #pragma unroll
    for (int i = 0; i < 4; i++) { gload_lds16(ga[i], &As[buf][(i*256 + wv*64)*8]); ga[i] += 64; }
    #pragma unroll
    for (int i = 0; i < 2; i++) { gload_lds16(gw[i], &Ws[buf][(i*256 + wv*64)*8]); gw[i] += 64; }
  };

  f32x4 acc[2][4];
  #pragma unroll
  for (int mi = 0; mi < 2; mi++)
    #pragma unroll
    for (int nj = 0; nj < 4; nj++) acc[mi][nj] = (f32x4){0.f,0.f,0.f,0.f};

  stage(0);
  const int iters = K >> 6;
  for (int it = 0; it < iters; it++) {
    const int cur = it & 1;
    __syncthreads();
    if (it + 1 < iters) stage(cur ^ 1);
    #pragma unroll
    for (int ks = 0; ks < 2; ks++) {
      const int cb = ((ks*4 + quad) ^ (m & 7)) << 3;
      bf16x8 af[2], wf[4];
      #pragma unroll
      for (int mi = 0; mi < 2; mi++)
        af[mi] = *(const bf16x8*)(&As[cur][(wv*32 + mi*16 + m) * 64 + cb]);
      #pragma unroll
      for (int nj = 0; nj < 4; nj++)
        wf[nj] = *(const bf16x8*)(&Ws[cur][(nj*16 + m) * 64 + cb]);
      #pragma unroll
      for (int mi = 0; mi < 2; mi++)
        #pragma unroll
        for (int nj = 0; nj < 4; nj++)
          acc[mi][nj] = __builtin_amdgcn_mfma_f32_16x16x32_bf16(af[mi], wf[nj], acc[mi][nj], 0, 0, 0);
    }
  }

  #pragma unroll
  for (int mi = 0; mi < 2; mi++)
    #pragma unroll
    for (int nj = 0; nj < 4; nj++) {
      const int col = bn + nj*16 + m;
      if (col < N) {
        #pragma unroll
        for (int r = 0; r < 4; r++) {
          const int row = bm + wv*32 + mi*16 + quad*4 + r;
          if constexpr (sizeof(CT) == 2)
            C[(size_t)row * N + col] = (CT)__float2bfloat16(acc[mi][nj][r]);
          else
            C[(size_t)row * N + col] = acc[mi][nj][r];
        }
      }
    }
}

// ---- merged Wq(+fused RMSNorm/RoPE) and Wkva GEMM: one launch, K=1024 ----
// q prescale folds log2(e): attention softmax runs in exp2 domain.
__global__ __launch_bounds__(256, 2)
void gemm_qkva(const __hip_bfloat16* __restrict__ A, const __hip_bfloat16* __restrict__ Wqb,
               const __hip_bfloat16* __restrict__ Wkvab,
               const float* __restrict__ qw, const float* __restrict__ cosp,
               const float* __restrict__ sinp,
               __hip_bfloat16* __restrict__ qb, float* __restrict__ kva)
{
  __shared__ __hip_bfloat16 As[2][128 * 64];
  __shared__ __hip_bfloat16 Ws[2][64 * 64];
  const int K = 1024;
  const int tid = threadIdx.x;
  const int wv = tid >> 6, lane = tid & 63;
  const int m = lane & 15, quad = lane >> 4;
  const int bm = blockIdx.y * 128;
  const bool isq = blockIdx.x < 16;
  const __hip_bfloat16* W = isq ? Wqb : Wkvab;
  const int bn = isq ? blockIdx.x*64 : (blockIdx.x - 16)*64;
  const int Nw = isq ? 1024 : 144;

  const __hip_bfloat16* ga[4];
  const __hip_bfloat16* gw[2];
  #pragma unroll
  for (int i = 0; i < 4; i++) {
    const int slot = i*256 + tid;
    const int row = slot >> 3, cb = slot & 7;
    ga[i] = A + (size_t)(bm + row) * K + ((cb ^ (row & 7)) << 3);
  }
  #pragma unroll
  for (int i = 0; i < 2; i++) {
    const int slot = i*256 + tid;
    const int row = slot >> 3, cb = slot & 7;
    int wr = bn + row; if (wr >= Nw) wr = Nw - 1;
    gw[i] = W + (size_t)wr * K + ((cb ^ (row & 7)) << 3);
  }
  auto stage = [&](int buf){
    #pragma unroll
    for (int i = 0; i < 4; i++) { gload_lds16(ga[i], &As[buf][(i*256 + wv*64)*8]); ga[i] += 64; }
    #pragma unroll
    for (int i = 0; i < 2; i++) { gload_lds16(gw[i], &Ws[buf][(i*256 + wv*64)*8]); gw[i] += 64; }
  };

  f32x4 acc[2][4];
  #pragma unroll
  for (int mi = 0; mi < 2; mi++)
    #pragma unroll
    for (int nj = 0; nj < 4; nj++) acc[mi][nj] = (f32x4){0.f,0.f,0.f,0.f};

  stage(0);
  for (int it = 0; it < 16; it++) {
    const int cur = it & 1;
    __syncthreads();
    if (it < 15) stage(cur ^ 1);
    #pragma unroll
    for (int ks = 0; ks < 2; ks++) {
      const int cb = ((ks*4 + quad) ^ (m & 7)) << 3;
      bf16x8 af[2], wf[4];
      #pragma unroll
      for (int mi = 0; mi < 2; mi++)
        af[mi] = *(const bf16x8*)(&As[cur][(wv*32 + mi*16 + m) * 64 + cb]);
      #pragma unroll
      for (int nj = 0; nj < 4; nj++)
        wf[nj] = *(const bf16x8*)(&Ws[cur][(nj*16 + m) * 64 + cb]);
      #pragma unroll
      for (int mi = 0; mi < 2; mi++)
        #pragma unroll
        for (int nj = 0; nj < 4; nj++)
          acc[mi][nj] = __builtin_amdgcn_mfma_f32_16x16x32_bf16(af[mi], wf[nj], acc[mi][nj], 0, 0, 0);
    }
  }

  if (isq) {
    const int head = blockIdx.x;
    float qwv[4];
    #pragma unroll
    for (int nj = 0; nj < 4; nj++) qwv[nj] = qw[nj*16 + m];
    const int j = m & 7;
    const float qscale = 0.125f * 1.44269504f;
    #pragma unroll
    for (int mi = 0; mi < 2; mi++) {
      #pragma unroll
      for (int r = 0; r < 4; r++) {
        float ss = 0.f;
        #pragma unroll
        for (int nj = 0; nj < 4; nj++) { const float t = acc[mi][nj][r]; ss = fmaf(t, t, ss); }
        ss += __shfl_xor(ss, 1, 64); ss += __shfl_xor(ss, 2, 64);
        ss += __shfl_xor(ss, 4, 64); ss += __shfl_xor(ss, 8, 64);
        const float nrm = rsqrtf(ss * (1.0f/64.0f) + EPS);
        float v[4];
        #pragma unroll
        for (int nj = 0; nj < 4; nj++) v[nj] = acc[mi][nj][r] * nrm * qwv[nj];
        const int grow = bm + wv*32 + mi*16 + quad*4 + r;
        const int t = grow & (T_ - 1);
        const int b = grow >> 11;
        const float part = __shfl_xor(v[3], 8, 64);
        const float c = cosp[t*8 + j], sn = sinp[t*8 + j];
        v[3] = (m < 8) ? (v[3]*c - part*sn) : (v[3]*c + part*sn);
        __hip_bfloat16* dst = qb + ((size_t)(b*NH + head)*T_ + t)*64 + m;
        #pragma unroll
        for (int nj = 0; nj < 4; nj++) dst[nj*16] = __float2bfloat16(v[nj] * qscale);
      }
    }
  } else {
    #pragma unroll
    for (int mi = 0; mi < 2; mi++)
      #pragma unroll
      for (int nj = 0; nj < 4; nj++) {
        const int col = bn + nj*16 + m;
        if (col < 144) {
          #pragma unroll
          for (int r = 0; r < 4; r++) {
            const int row = bm + wv*32 + mi*16 + quad*4 + r;
            kva[(size_t)row * 144 + col] = acc[mi][nj][r];
          }
        }
      }
  }
}

// Per (b,t): RMSNorm over kv_a[:128] -> kvl16; RoPE on kv_a[128:144] -> krope16.
__global__ void prep_kv(const float* __restrict__ kva, const float* __restrict__ kw,
                        const float* __restrict__ cosp, const float* __restrict__ sinp,
                        __hip_bfloat16* __restrict__ kvl16, __hip_bfloat16* __restrict__ krope16)
{
  const int tid = threadIdx.x;   // 0..127
  const int bt = blockIdx.x;
  const int t = bt % T_;
  const float* row = kva + (size_t)bt * 144;
  const float v = row[tid];
  float s = wred_sum(v * v);
  __shared__ float red[2];
  if ((tid & 63) == 0) red[tid >> 6] = s;
  __syncthreads();
  const float total = red[0] + red[1];
  const float norm = rsqrtf(total * (1.0f/128.0f) + EPS);
  kvl16[(size_t)bt * 128 + tid] = __float2bfloat16(v * norm * kw[tid]);
  if (tid < 16) {
    const int j = tid & 7;
    const float c = cosp[t*8 + j], sn = sinp[t*8 + j];
    const float x1 = row[128 + j], x2 = row[136 + j];
    krope16[(size_t)bt * 16 + tid] = __float2bfloat16((tid < 8) ? (x1 * c - x2 * sn)
                                                               : (x2 * c + x1 * sn));
  }
}

// ---- kvb GEMM (K=128, N=1792 permuted) with fused outputs ----
__global__ __launch_bounds__(256, 2)
void gemm_kvb(const __hip_bfloat16* __restrict__ A, const __hip_bfloat16* __restrict__ W,
              __hip_bfloat16* __restrict__ knope, __hip_bfloat16* __restrict__ vt)
{
  __shared__ __hip_bfloat16 As[2][128 * 64];
  __shared__ __hip_bfloat16 Ws[2][64 * 64];
  const int K = 128;
  const int tid = threadIdx.x;
  const int wv = tid >> 6, lane = tid & 63;
  const int m = lane & 15, quad = lane >> 4;
  const int bm = blockIdx.y * 128, bn = blockIdx.x * 64;

  const __hip_bfloat16* ga[4];
  const __hip_bfloat16* gw[2];
  #pragma unroll
  for (int i = 0; i < 4; i++) {
    const int slot = i*256 + tid;
    const int row = slot >> 3, cb = slot & 7;
    ga[i] = A + (size_t)(bm + row) * K + ((cb ^ (row & 7)) << 3);
  }
  #pragma unroll
  for (int i = 0; i < 2; i++) {
    const int slot = i*256 + tid;
    const int row = slot >> 3, cb = slot & 7;
    gw[i] = W + (size_t)(bn + row) * K + ((cb ^ (row & 7)) << 3);
  }
  auto stage = [&](int buf){
    #pragma unroll
    for (int i = 0; i < 4; i++) { gload_lds16(ga[i], &As[buf][(i*256 + wv*64)*8]); ga[i] += 64; }
    #pragma unroll
    for (int i = 0; i < 2; i++) { gload_lds16(gw[i], &Ws[buf][(i*256 + wv*64)*8]); gw[i] += 64; }
  };

  f32x4 acc[2][4];
  #pragma unroll
  for (int mi = 0; mi < 2; mi++)
    #pragma unroll
    for (int nj = 0; nj < 4; nj++) acc[mi][nj] = (f32x4){0.f,0.f,0.f,0.f};

  stage(0);
  for (int it = 0; it < 2; it++) {
    const int cur = it & 1;
    __syncthreads();
    if (it == 0) stage(1);
    #pragma unroll
    for (int ks = 0; ks < 2; ks++) {
      const int cb = ((ks*4 + quad) ^ (m & 7)) << 3;
      bf16x8 af[2], wf[4];
      #pragma unroll
      for (int mi = 0; mi < 2; mi++)
        af[mi] = *(const bf16x8*)(&As[cur][(wv*32 + mi*16 + m) * 64 + cb]);
      #pragma unroll
      for (int nj = 0; nj < 4; nj++)
        wf[nj] = *(const bf16x8*)(&Ws[cur][(nj*16 + m) * 64 + cb]);
      #pragma unroll
      for (int mi = 0; mi < 2; mi++)
        #pragma unroll
        for (int nj = 0; nj < 4; nj++)
          acc[mi][nj] = __builtin_amdgcn_mfma_f32_16x16x32_bf16(af[mi], wf[nj], acc[mi][nj], 0, 0, 0);
    }
  }

  if (bn < 768) {
    #pragma unroll
    for (int mi = 0; mi < 2; mi++)
      #pragma unroll
      for (int nj = 0; nj < 4; nj++) {
        const int col = bn + nj*16 + m;
        #pragma unroll
        for (int r = 0; r < 4; r++) {
          const int row = bm + wv*32 + mi*16 + quad*4 + r;
          knope[(size_t)row * 768 + col] = __float2bfloat16(acc[mi][nj][r]);
        }
      }
  } else {
    __syncthreads();
    short* TL = (short*)&As[0][0];          // [64 d][pitch 136]
    #pragma unroll
    for (int mi = 0; mi < 2; mi++)
      #pragma unroll
      for (int nj = 0; nj < 4; nj++) {
        const int d = nj*16 + m;
        #pragma unroll
        for (int r = 0; r < 4; r++) {
          const int tl = wv*32 + mi*16 + quad*4 + r;
          __hip_bfloat16 hv = __float2bfloat16(acc[mi][nj][r]);
          short sv; __builtin_memcpy(&sv, &hv, 2);
          TL[d*136 + tl] = sv;
        }
      }
    __syncthreads();
    const int h = (bn - 768) >> 6;
    const int b = bm >> 11;
    const int t0 = bm & (T_ - 1);
    #pragma unroll
    for (int i = 0; i < 4; i++) {
      const int unit = i*256 + tid;        // 1024 units of 8 elems
      const int d = unit >> 4, tu = unit & 15;
      *(bf16x8*)(vt + ((size_t)(b*NH + h)*64 + d)*T_ + t0 + tu*8)
          = *(const bf16x8*)(TL + d*136 + tu*8);
    }
  }
}

// 2x2 wave-split flash attention, DIAGONAL PEEL, bare v_exp_f32 softmax.
// DETERMINISM HARDENING (R15): PV now uses the guaranteed builtin
// mfma_f32_16x16x32_bf16 with ZERO-PADDED fragments (physical k=quad*8+{0..3}
// carries the 16 logical keys; k=quad*8+{4..7} zero on BOTH A and B sides) —
// reproduces the former 16x16x16 contraction exactly with compiler-managed
// MFMA hazard wait-states. No inline asm remains in the binary.
__global__ __launch_bounds__(256, 4)
void attn_tile(const __hip_bfloat16* __restrict__ qb,
               const __hip_bfloat16* __restrict__ knope,
               const __hip_bfloat16* __restrict__ krope16,
               const __hip_bfloat16* __restrict__ vt16,
               __hip_bfloat16* __restrict__ aout)
{
  __shared__ __hip_bfloat16 SL[16384];  // K [2][64][64] @0/4096, V [2][64][64] @8192/12288
  const int tid = threadIdx.x;
  const int wv = tid >> 6, lane = tid & 63;
  const int m = lane & 15, quad = lane >> 4;
  const int wq = wv >> 1, wk = wv & 1;
  const int idx = (blockIdx.x + blockIdx.y) & 31;
  const int pj = idx & 7, pk = idx >> 3;
  const int qt = (pk == 0) ? pj : (pk == 1) ? (15 - pj) : (pk == 2) ? (16 + pj) : (31 - pj);
  const int bh = blockIdx.y;
  const int b = bh >> 4, h = bh & 15;
  const int nt = qt + 1;

  // Q for this wave's 32 q-rows (2 x 16-row tiles)
  bf16x8 q0[2], q1[2];
  #pragma unroll
  for (int t2 = 0; t2 < 2; t2++) {
    const __hip_bfloat16* qr = qb + ((size_t)bh*T_ + qt*64 + wq*32 + t2*16 + m)*64 + quad*8;
    q0[t2] = *(const bf16x8*)qr; q1[t2] = *(const bf16x8*)(qr + 32);
  }

  const __hip_bfloat16* pK[2]; size_t iK[2];
  const __hip_bfloat16* pV[2];
  #pragma unroll
  for (int i = 0; i < 2; i++) {
    const int slot = i*256 + tid;
    const int krow = slot >> 3;                 // 0..63: K row (key) / V row (d)
    const int kde = (slot & 7) ^ (krow & 7);
    if (kde < 6) { pK[i] = knope + (size_t)(b*T_ + krow)*768 + h*48 + kde*8; iK[i] = (size_t)64*768; }
    else         { pK[i] = krope16 + (size_t)(b*T_ + krow)*16 + (kde-6)*8;   iK[i] = (size_t)64*16; }
    pV[i] = vt16 + ((size_t)bh*64 + krow)*T_ + kde*8;
  }

  auto stage = [&](int buf){
    #pragma unroll
    for (int i = 0; i < 2; i++) {
      gload_lds16(pK[i], SL + buf*4096 + (i*256 + wv*64)*8);
      gload_lds16(pV[i], SL + 8192 + buf*4096 + (i*256 + wv*64)*8);
      pK[i] += iK[i]; pV[i] += 64;
    }
  };

  f32x4 o[2][4];
  #pragma unroll
  for (int t2 = 0; t2 < 2; t2++)
    #pragma unroll
    for (int vs = 0; vs < 4; vs++) o[t2][vs] = (f32x4){0.f,0.f,0.f,0.f};
  float lrun[2] = {0.f, 0.f};

  const int swk = quad ^ (m & 7);
  const int qh = quad >> 1, ql = quad & 1;
  stage(0);

  // ---- maskless main loop: kt = 0 .. nt-2 ----
  for (int kt = 0; kt < nt - 1; kt++) {
    const int cur = kt & 1;
    __syncthreads();
    stage(cur ^ 1);
    const __hip_bfloat16* Kc = SL + cur*4096;
    const __hip_bfloat16* Vc = SL + 8192 + cur*4096;

    f32x4 s[2][2];
    __builtin_amdgcn_s_setprio(1);
    #pragma unroll
    for (int ks = 0; ks < 2; ks++) {
      const __hip_bfloat16* kr = Kc + (wk*32 + ks*16 + m)*64;
      const bf16x8 kf0 = *(const bf16x8*)(kr + swk*8);
      const bf16x8 kf1 = *(const bf16x8*)(kr + (swk^4)*8);
      #pragma unroll
      for (int t2 = 0; t2 < 2; t2++) {
        f32x4 z = (f32x4){0.f,0.f,0.f,0.f};
        z = __builtin_amdgcn_mfma_f32_16x16x32_bf16(kf0, q0[t2], z, 0, 0, 0);
        z = __builtin_amdgcn_mfma_f32_16x16x32_bf16(kf1, q1[t2], z, 0, 0, 0);
        s[t2][ks] = z;
      }
    }
    __builtin_amdgcn_s_setprio(0);

    bf16x8 u8[2][2];
    #pragma unroll
    for (int t2 = 0; t2 < 2; t2++)
      #pragma unroll
      for (int ks = 0; ks < 2; ks++) {
        float p0 = fexp2(s[t2][ks][0] - 48.0f), p1 = fexp2(s[t2][ks][1] - 48.0f);
        float p2 = fexp2(s[t2][ks][2] - 48.0f), p3 = fexp2(s[t2][ks][3] - 48.0f);
        lrun[t2] += (p0 + p1) + (p2 + p3);
        union { unsigned ui[4]; bf16x8 v; } uu;
        uu.ui[0] = pack_bf16(p0, p1);
        uu.ui[1] = pack_bf16(p2, p3);
        uu.ui[2] = 0; uu.ui[3] = 0;
        u8[t2][ks] = uu.v;
      }

    __builtin_amdgcn_s_setprio(1);
    #pragma unroll
    for (int vs = 0; vs < 4; vs++)
      #pragma unroll
      for (int ks = 0; ks < 2; ks++) {
        const bf16x4 vf = *(const bf16x4*)(Vc + (vs*16 + m)*64
                            + (((wk*4 + ks*2 + qh) ^ (m & 7)) << 3) + (ql << 2));
        union { bf16x4 h2[2]; bf16x8 v8; } av;
        av.h2[0] = vf; av.h2[1] = (bf16x4){0,0,0,0};
        #pragma unroll
        for (int t2 = 0; t2 < 2; t2++)
          o[t2][vs] = __builtin_amdgcn_mfma_f32_16x16x32_bf16(av.v8, u8[t2][ks], o[t2][vs], 0, 0, 0);
      }
    __builtin_amdgcn_s_setprio(0);
  }

  // ---- peeled diagonal tile: kt = qt (causal masking lives only here) ----
  {
    const int cur = (nt - 1) & 1;
    __syncthreads();
    const __hip_bfloat16* Kc = SL + cur*4096;
    const __hip_bfloat16* Vc = SL + 8192 + cur*4096;

    f32x4 s[2][2];
    __builtin_amdgcn_s_setprio(1);
    #pragma unroll
    for (int ks = 0; ks < 2; ks++) {
      const int gk2 = 2*wk + ks;
      if (gk2 <= 2*wq + 1) {
        const __hip_bfloat16* kr = Kc + (wk*32 + ks*16 + m)*64;
        const bf16x8 kf0 = *(const bf16x8*)(kr + swk*8);
        const bf16x8 kf1 = *(const bf16x8*)(kr + (swk^4)*8);
        #pragma unroll
        for (int t2 = 0; t2 < 2; t2++) {
          if (gk2 <= 2*wq + t2) {
            f32x4 z = (f32x4){0.f,0.f,0.f,0.f};
            z = __builtin_amdgcn_mfma_f32_16x16x32_bf16(kf0, q0[t2], z, 0, 0, 0);
            z = __builtin_amdgcn_mfma_f32_16x16x32_bf16(kf1, q1[t2], z, 0, 0, 0);
            s[t2][ks] = z;
          } else {
            s[t2][ks] = (f32x4){-1e30f,-1e30f,-1e30f,-1e30f};
          }
        }
      } else {
        s[0][ks] = (f32x4){-1e30f,-1e30f,-1e30f,-1e30f};
        s[1][ks] = (f32x4){-1e30f,-1e30f,-1e30f,-1e30f};
      }
    }
    __builtin_amdgcn_s_setprio(0);

    #pragma unroll
    for (int ks = 0; ks < 2; ks++)
      #pragma unroll
      for (int t2 = 0; t2 < 2; t2++)
        if (2*wk + ks == 2*wq + t2) {            // diagonal 16-block: element mask
          #pragma unroll
          for (int r = 0; r < 4; r++)
            if (quad*4 + r > m) s[t2][ks][r] = -1e30f;
        }

    bf16x8 u8[2][2];
    #pragma unroll
    for (int t2 = 0; t2 < 2; t2++)
      #pragma unroll
      for (int ks = 0; ks < 2; ks++) {
        float p0 = fexp2(s[t2][ks][0] - 48.0f), p1 = fexp2(s[t2][ks][1] - 48.0f);
        float p2 = fexp2(s[t2][ks][2] - 48.0f), p3 = fexp2(s[t2][ks][3] - 48.0f);
        lrun[t2] += (p0 + p1) + (p2 + p3);
        union { unsigned ui[4]; bf16x8 v; } uu;
        uu.ui[0] = pack_bf16(p0, p1);
        uu.ui[1] = pack_bf16(p2, p3);
        uu.ui[2] = 0; uu.ui[3] = 0;
        u8[t2][ks] = uu.v;
      }

    __builtin_amdgcn_s_setprio(1);
    #pragma unroll
    for (int vs = 0; vs < 4; vs++)
      #pragma unroll
      for (int ks = 0; ks < 2; ks++) {
        const int gk2 = 2*wk + ks;
        if (gk2 <= 2*wq + 1) {
          const bf16x4 vf = *(const bf16x4*)(Vc + (vs*16 + m)*64
                              + (((wk*4 + ks*2 + qh) ^ (m & 7)) << 3) + (ql << 2));
          union { bf16x4 h2[2]; bf16x8 v8; } av;
          av.h2[0] = vf; av.h2[1] = (bf16x4){0,0,0,0};
          #pragma unroll
          for (int t2 = 0; t2 < 2; t2++)
            if (gk2 <= 2*wq + t2)
              o[t2][vs] = __builtin_amdgcn_mfma_f32_16x16x32_bf16(av.v8, u8[t2][ks], o[t2][vs], 0, 0, 0);
        }
      }
    __builtin_amdgcn_s_setprio(0);
  }

  // combine wk partners (partials over disjoint key sets sum exactly), store
  __syncthreads();
  float* FB = (float*)SL;               // 4096 floats (reuses K region)
  float* LB = ((float*)SL) + 4096;      // 256 floats (start of V region)
  if (wk == 1) {
    #pragma unroll
    for (int t2 = 0; t2 < 2; t2++)
      #pragma unroll
      for (int vs = 0; vs < 4; vs++)
        #pragma unroll
        for (int r = 0; r < 4; r++)
          FB[wq*2048 + ((t2*4 + vs)*4 + r)*64 + lane] = o[t2][vs][r];
    LB[wq*128 + lane]      = lrun[0];
    LB[wq*128 + 64 + lane] = lrun[1];
  }
  __syncthreads();
  if (wk == 0) {
    #pragma unroll
    for (int t2 = 0; t2 < 2; t2++)
      #pragma unroll
      for (int vs = 0; vs < 4; vs++)
        #pragma unroll
        for (int r = 0; r < 4; r++)
          o[t2][vs][r] += FB[wq*2048 + ((t2*4 + vs)*4 + r)*64 + lane];
    lrun[0] += LB[wq*128 + lane];
    lrun[1] += LB[wq*128 + 64 + lane];
    #pragma unroll
    for (int t2 = 0; t2 < 2; t2++) {
      float l = lrun[t2];
      l += __shfl_xor(l, 16, 64);
      l += __shfl_xor(l, 32, 64);
      const float inv = 1.0f / l;
      const size_t base = (size_t)(b*T_ + qt*64 + wq*32 + t2*16 + m) * 1024 + h*64 + quad*4;
      #pragma unroll
      for (int vs = 0; vs < 4; vs++) {
        union { unsigned ui[2]; bf16x4 v; } pkv;
        pkv.ui[0] = pack_bf16(o[t2][vs][0] * inv, o[t2][vs][1] * inv);
        pkv.ui[1] = pack_bf16(o[t2][vs][2] * inv, o[t2][vs][3] * inv);
        *(bf16x4*)(aout + base + vs*16) = pkv.v;
      }
    }
  }
}

extern "C" void kernel_launch(void* const* d_in, const int* in_sizes, int n_in,
                              void* d_out, int out_size, void* d_ws, size_t ws_size,
                              hipStream_t stream)
{
  const float* x    = (const float*)d_in[0];
  const float* cosp = (const float*)d_in[1];
  const float* sinp = (const float*)d_in[2];
  const float* Wq   = (const float*)d_in[3];
  const float* qw   = (const float*)d_in[4];
  const float* Wkva = (const float*)d_in[5];
  const float* kw   = (const float*)d_in[6];
  const float* Wkvb = (const float*)d_in[7];
  const float* Wo   = (const float*)d_in[8];
  float* out = (float*)d_out;

  float* kva = (float*)d_ws;                                  //   589,824 f
  __hip_bfloat16* xb16    = (__hip_bfloat16*)(kva + 589824);  // 4,194,304
  __hip_bfloat16* knope16 = xb16 + 4194304;                   // 3,145,728
  __hip_bfloat16* kvl16   = knope16 + 3145728;                //   524,288
  __hip_bfloat16* qb16    = kvl16 + 524288;                   // 4,194,304
  __hip_bfloat16* vt16    = qb16 + 4194304;                   // 4,194,304
  __hip_bfloat16* krope16 = vt16 + 4194304;                   //    65,536
  __hip_bfloat16* Wqb     = krope16 + 65536;                  // 1,048,576
  __hip_bfloat16* Wkvab   = Wqb + 1048576;                    //   147,456
  __hip_bfloat16* Wkvbb   = Wkvab + 147456;                   //   229,376
  __hip_bfloat16* Wob     = Wkvbb + 229376;                   // 1,048,576
  __hip_bfloat16* ab16    = Wob + 1048576;                    // 4,194,304

  const int M = B_ * T_;   // 4096

  cvt5<<<6512, 256, 0, stream>>>(x, Wq, Wkva, Wkvb, Wo, xb16, Wqb, Wkvab, Wkvbb, Wob);
  gemm_qkva<<<dim3(19, 32), 256, 0, stream>>>(xb16, Wqb, Wkvab, qw, cosp, sinp, qb16, kva);
  prep_kv<<<M, 128, 0, stream>>>(kva, kw, cosp, sinp, kvl16, krope16);
  gemm_kvb<<<dim3(28, 32), 256, 0, stream>>>(kvl16, Wkvbb, knope16, vt16);
  attn_tile<<<dim3(32, B_ * NH), 256, 0, stream>>>(qb16, knope16, krope16, vt16, ab16);
  gemm_bt64<float><<<dim3(16, 32), 256, 0, stream>>>(ab16, Wob, out, M, 1024, 1024);
}

// Round 20
// 171.889 us; speedup vs baseline: 1.0027x; 1.0027x over previous
//
#include <hip/hip_runtime.h>
#include <hip/hip_bf16.h>
#include <math.h>

#define NH 16
#define T_ 2048
#define B_ 2
#define D_ 1024
#define EPS 1e-6f

typedef __attribute__((ext_vector_type(8))) short bf16x8;
typedef __attribute__((ext_vector_type(4))) short bf16x4;
typedef __attribute__((ext_vector_type(4))) float f32x4;

__device__ __forceinline__ float wred_sum(float v){
  #pragma unroll
  for (int o = 32; o > 0; o >>= 1) v += __shfl_xor(v, o, 64);
  return v;
}

__device__ __forceinline__ unsigned pack_bf16(float a, float b){
  __hip_bfloat162 t = __float22bfloat162_rn(make_float2(a, b));
  unsigned r; __builtin_memcpy(&r, &t, 4); return r;
}

// Bare v_exp_f32 (2^x), UNCONDITIONAL builtin (no inline asm in this file).
__device__ __forceinline__ float fexp2(float x){
  return __builtin_amdgcn_exp2f(x);
}

__device__ __forceinline__ void gload_lds16(const void* g, void* l){
  __builtin_amdgcn_global_load_lds((const __attribute__((address_space(1))) void*)g,
                                   (__attribute__((address_space(3))) void*)l, 16, 0, 0);
}

// R19 DETERMINISM HARDENING: force-drain ALL counters (vmcnt included — the
// async global_load_lds LDS-writes are vmcnt-tracked) before every barrier.
// If the compiler already drains, this retires free; if not, it closes the
// only remaining timing-dependent race candidate (stale LDS reads in the
// double-buffered staging loops — matches the batch0/high-t divergence
// signature of the intermittent tripwire).
__device__ __forceinline__ void barrier_full(){
  __builtin_amdgcn_s_waitcnt(0);
  __syncthreads();
}

// ---- convert x + weights to bf16; Wkvb rows PERMUTED: [h*48+d | 768+h*64+dv] ----
__global__ __launch_bounds__(256)
void cvt5(const float* __restrict__ x, const float* __restrict__ wq,
          const float* __restrict__ wkva, const float* __restrict__ wkvb,
          const float* __restrict__ wo,
          __hip_bfloat16* __restrict__ xb, __hip_bfloat16* __restrict__ wqb,
          __hip_bfloat16* __restrict__ wkvab, __hip_bfloat16* __restrict__ wkvbb,
          __hip_bfloat16* __restrict__ wob)
{
  const int i = blockIdx.x * 256 + threadIdx.x;     // float4 index, 1,667,072 total
  const float* s; __hip_bfloat16* d; size_t soff, doff;
  if      (i < 1048576) { s = x;    d = xb;    soff = doff = i; }
  else if (i < 1310720) { s = wq;   d = wqb;   soff = doff = i - 1048576; }
  else if (i < 1347584) { s = wkva; d = wkvab; soff = doff = i - 1310720; }
  else if (i < 1404928) {
    const int off = i - 1347584;                    // float4 idx into 1792x128
    const int srow = off >> 5, c4 = off & 31;
    const int h = srow / 112, dd = srow % 112;
    const int drow = (dd < 48) ? (h*48 + dd) : (768 + h*64 + (dd - 48));
    s = wkvb; d = wkvbb; soff = off; doff = (size_t)drow*32 + c4;
  }
  else                  { s = wo;   d = wob;   soff = doff = i - 1404928; }
  float4 v = *(const float4*)(s + soff * 4);
  *(__hip_bfloat162*)(d + doff * 4)     = __float22bfloat162_rn(make_float2(v.x, v.y));
  *(__hip_bfloat162*)(d + doff * 4 + 2) = __float22bfloat162_rn(make_float2(v.z, v.w));
}

// ---- bf16 MFMA GEMM, 128x64 tile, DOUBLE-BUFFERED staging (48KB LDS) ----
template<typename CT>
__global__ __launch_bounds__(256, 2)
void gemm_bt64(const __hip_bfloat16* __restrict__ A, const __hip_bfloat16* __restrict__ W,
               CT* __restrict__ C, int M, int N, int K)
{
  __shared__ __hip_bfloat16 As[2][128 * 64];   // 32 KB
  __shared__ __hip_bfloat16 Ws[2][64 * 64];    // 16 KB
  const int tid = threadIdx.x;
  const int wv = tid >> 6, lane = tid & 63;
  const int m = lane & 15, quad = lane >> 4;
  const int bm = blockIdx.y * 128, bn = blockIdx.x * 64;

  const __hip_bfloat16* ga[4];
  const __hip_bfloat16* gw[2];
  #pragma unroll
  for (int i = 0; i < 4; i++) {
    const int slot = i*256 + tid;
    const int row = slot >> 3, cb = slot & 7;
    ga[i] = A + (size_t)(bm + row) * K + ((cb ^ (row & 7)) << 3);
  }
  #pragma unroll
  for (int i = 0; i < 2; i++) {
    const int slot = i*256 + tid;
    const int row = slot >> 3, cb = slot & 7;
    int wr = bn + row; if (wr >= N) wr = N - 1;
    gw[i] = W + (size_t)wr * K + ((cb ^ (row & 7)) << 3);
  }
  auto stage = [&](int buf){
    #pragma unroll
    for (int i = 0; i < 4; i++) { gload_lds16(ga[i], &As[buf][(i*256 + wv*64)*8]); ga[i] += 64; }
    #pragma unroll
    for (int i = 0; i < 2; i++) { gload_lds16(gw[i], &Ws[buf][(i*256 + wv*64)*8]); gw[i] += 64; }
  };

  f32x4 acc[2][4];
  #pragma unroll
  for (int mi = 0; mi < 2; mi++)
    #pragma unroll
    for (int nj = 0; nj < 4; nj++) acc[mi][nj] = (f32x4){0.f,0.f,0.f,0.f};

  stage(0);
  const int iters = K >> 6;
  for (int it = 0; it < iters; it++) {
    const int cur = it & 1;
    barrier_full();
    if (it + 1 < iters) stage(cur ^ 1);
    #pragma unroll
    for (int ks = 0; ks < 2; ks++) {
      const int cb = ((ks*4 + quad) ^ (m & 7)) << 3;
      bf16x8 af[2], wf[4];
      #pragma unroll
      for (int mi = 0; mi < 2; mi++)
        af[mi] = *(const bf16x8*)(&As[cur][(wv*32 + mi*16 + m) * 64 + cb]);
      #pragma unroll
      for (int nj = 0; nj < 4; nj++)
        wf[nj] = *(const bf16x8*)(&Ws[cur][(nj*16 + m) * 64 + cb]);
      #pragma unroll
      for (int mi = 0; mi < 2; mi++)
        #pragma unroll
        for (int nj = 0; nj < 4; nj++)
          acc[mi][nj] = __builtin_amdgcn_mfma_f32_16x16x32_bf16(af[mi], wf[nj], acc[mi][nj], 0, 0, 0);
    }
  }

  #pragma unroll
  for (int mi = 0; mi < 2; mi++)
    #pragma unroll
    for (int nj = 0; nj < 4; nj++) {
      const int col = bn + nj*16 + m;
      if (col < N) {
        #pragma unroll
        for (int r = 0; r < 4; r++) {
          const int row = bm + wv*32 + mi*16 + quad*4 + r;
          if constexpr (sizeof(CT) == 2)
            C[(size_t)row * N + col] = (CT)__float2bfloat16(acc[mi][nj][r]);
          else
            C[(size_t)row * N + col] = acc[mi][nj][r];
        }
      }
    }
}

// ---- merged Wq(+fused RMSNorm/RoPE) and Wkva GEMM: one launch, K=1024 ----
// q prescale folds log2(e): attention softmax runs in exp2 domain.
__global__ __launch_bounds__(256, 2)
void gemm_qkva(const __hip_bfloat16* __restrict__ A, const __hip_bfloat16* __restrict__ Wqb,
               const __hip_bfloat16* __restrict__ Wkvab,
               const float* __restrict__ qw, const float* __restrict__ cosp,
               const float* __restrict__ sinp,
               __hip_bfloat16* __restrict__ qb, float* __restrict__ kva)
{
  __shared__ __hip_bfloat16 As[2][128 * 64];
  __shared__ __hip_bfloat16 Ws[2][64 * 64];
  const int K = 1024;
  const int tid = threadIdx.x;
  const int wv = tid >> 6, lane = tid & 63;
  const int m = lane & 15, quad = lane >> 4;
  const int bm = blockIdx.y * 128;
  const bool isq = blockIdx.x < 16;
  const __hip_bfloat16* W = isq ? Wqb : Wkvab;
  const int bn = isq ? blockIdx.x*64 : (blockIdx.x - 16)*64;
  const int Nw = isq ? 1024 : 144;

  const __hip_bfloat16* ga[4];
  const __hip_bfloat16* gw[2];
  #pragma unroll
  for (int i = 0; i < 4; i++) {
    const int slot = i*256 + tid;
    const int row = slot >> 3, cb = slot & 7;
    ga[i] = A + (size_t)(bm + row) * K + ((cb ^ (row & 7)) << 3);
  }
  #pragma unroll
  for (int i = 0; i < 2; i++) {
    const int slot = i*256 + tid;
    const int row = slot >> 3, cb = slot & 7;
    int wr = bn + row; if (wr >= Nw) wr = Nw - 1;
    gw[i] = W + (size_t)wr * K + ((cb ^ (row & 7)) << 3);
  }
  auto stage = [&](int buf){
    #pragma unroll
    for (int i = 0; i < 4; i++) { gload_lds16(ga[i], &As[buf][(i*256 + wv*64)*8]); ga[i] += 64; }
    #pragma unroll
    for (int i = 0; i < 2; i++) { gload_lds16(gw[i], &Ws[buf][(i*256 + wv*64)*8]); gw[i] += 64; }
  };

  f32x4 acc[2][4];
  #pragma unroll
  for (int mi = 0; mi < 2; mi++)
    #pragma unroll
    for (int nj = 0; nj < 4; nj++) acc[mi][nj] = (f32x4){0.f,0.f,0.f,0.f};

  stage(0);
  for (int it = 0; it < 16; it++) {
    const int cur = it & 1;
    barrier_full();
    if (it < 15) stage(cur ^ 1);
    #pragma unroll
    for (int ks = 0; ks < 2; ks++) {
      const int cb = ((ks*4 + quad) ^ (m & 7)) << 3;
      bf16x8 af[2], wf[4];
      #pragma unroll
      for (int mi = 0; mi < 2; mi++)
        af[mi] = *(const bf16x8*)(&As[cur][(wv*32 + mi*16 + m) * 64 + cb]);
      #pragma unroll
      for (int nj = 0; nj < 4; nj++)
        wf[nj] = *(const bf16x8*)(&Ws[cur][(nj*16 + m) * 64 + cb]);
      #pragma unroll
      for (int mi = 0; mi < 2; mi++)
        #pragma unroll
        for (int nj = 0; nj < 4; nj++)
          acc[mi][nj] = __builtin_amdgcn_mfma_f32_16x16x32_bf16(af[mi], wf[nj], acc[mi][nj], 0, 0, 0);
    }
  }

  if (isq) {
    const int head = blockIdx.x;
    float qwv[4];
    #pragma unroll
    for (int nj = 0; nj < 4; nj++) qwv[nj] = qw[nj*16 + m];
    const int j = m & 7;
    const float qscale = 0.125f * 1.44269504f;
    #pragma unroll
    for (int mi = 0; mi < 2; mi++) {
      #pragma unroll
      for (int r = 0; r < 4; r++) {
        float ss = 0.f;
        #pragma unroll
        for (int nj = 0; nj < 4; nj++) { const float t = acc[mi][nj][r]; ss = fmaf(t, t, ss); }
        ss += __shfl_xor(ss, 1, 64); ss += __shfl_xor(ss, 2, 64);
        ss += __shfl_xor(ss, 4, 64); ss += __shfl_xor(ss, 8, 64);
        const float nrm = rsqrtf(ss * (1.0f/64.0f) + EPS);
        float v[4];
        #pragma unroll
        for (int nj = 0; nj < 4; nj++) v[nj] = acc[mi][nj][r] * nrm * qwv[nj];
        const int grow = bm + wv*32 + mi*16 + quad*4 + r;
        const int t = grow & (T_ - 1);
        const int b = grow >> 11;
        const float part = __shfl_xor(v[3], 8, 64);
        const float c = cosp[t*8 + j], sn = sinp[t*8 + j];
        v[3] = (m < 8) ? (v[3]*c - part*sn) : (v[3]*c + part*sn);
        __hip_bfloat16* dst = qb + ((size_t)(b*NH + head)*T_ + t)*64 + m;
        #pragma unroll
        for (int nj = 0; nj < 4; nj++) dst[nj*16] = __float2bfloat16(v[nj] * qscale);
      }
    }
  } else {
    #pragma unroll
    for (int mi = 0; mi < 2; mi++)
      #pragma unroll
      for (int nj = 0; nj < 4; nj++) {
        const int col = bn + nj*16 + m;
        if (col < 144) {
          #pragma unroll
          for (int r = 0; r < 4; r++) {
            const int row = bm + wv*32 + mi*16 + quad*4 + r;
            kva[(size_t)row * 144 + col] = acc[mi][nj][r];
          }
        }
      }
  }
}

// Per (b,t): RMSNorm over kv_a[:128] -> kvl16; RoPE on kv_a[128:144] -> krope16.
__global__ void prep_kv(const float* __restrict__ kva, const float* __restrict__ kw,
                        const float* __restrict__ cosp, const float* __restrict__ sinp,
                        __hip_bfloat16* __restrict__ kvl16, __hip_bfloat16* __restrict__ krope16)
{
  const int tid = threadIdx.x;   // 0..127
  const int bt = blockIdx.x;
  const int t = bt % T_;
  const float* row = kva + (size_t)bt * 144;
  const float v = row[tid];
  float s = wred_sum(v * v);
  __shared__ float red[2];
  if ((tid & 63) == 0) red[tid >> 6] = s;
  __syncthreads();
  const float total = red[0] + red[1];
  const float norm = rsqrtf(total * (1.0f/128.0f) + EPS);
  kvl16[(size_t)bt * 128 + tid] = __float2bfloat16(v * norm * kw[tid]);
  if (tid < 16) {
    const int j = tid & 7;
    const float c = cosp[t*8 + j], sn = sinp[t*8 + j];
    const float x1 = row[128 + j], x2 = row[136 + j];
    krope16[(size_t)bt * 16 + tid] = __float2bfloat16((tid < 8) ? (x1 * c - x2 * sn)
                                                               : (x2 * c + x1 * sn));
  }
}

// ---- kvb GEMM (K=128, N=1792 permuted) with fused outputs ----
__global__ __launch_bounds__(256, 2)
void gemm_kvb(const __hip_bfloat16* __restrict__ A, const __hip_bfloat16* __restrict__ W,
              __hip_bfloat16* __restrict__ knope, __hip_bfloat16* __restrict__ vt)
{
  __shared__ __hip_bfloat16 As[2][128 * 64];
  __shared__ __hip_bfloat16 Ws[2][64 * 64];
  const int K = 128;
  const int tid = threadIdx.x;
  const int wv = tid >> 6, lane = tid & 63;
  const int m = lane & 15, quad = lane >> 4;
  const int bm = blockIdx.y * 128, bn = blockIdx.x * 64;

  const __hip_bfloat16* ga[4];
  const __hip_bfloat16* gw[2];
  #pragma unroll
  for (int i = 0; i < 4; i++) {
    const int slot = i*256 + tid;
    const int row = slot >> 3, cb = slot & 7;
    ga[i] = A + (size_t)(bm + row) * K + ((cb ^ (row & 7)) << 3);
  }
  #pragma unroll
  for (int i = 0; i < 2; i++) {
    const int slot = i*256 + tid;
    const int row = slot >> 3, cb = slot & 7;
    gw[i] = W + (size_t)(bn + row) * K + ((cb ^ (row & 7)) << 3);
  }
  auto stage = [&](int buf){
    #pragma unroll
    for (int i = 0; i < 4; i++) { gload_lds16(ga[i], &As[buf][(i*256 + wv*64)*8]); ga[i] += 64; }
    #pragma unroll
    for (int i = 0; i < 2; i++) { gload_lds16(gw[i], &Ws[buf][(i*256 + wv*64)*8]); gw[i] += 64; }
  };

  f32x4 acc[2][4];
  #pragma unroll
  for (int mi = 0; mi < 2; mi++)
    #pragma unroll
    for (int nj = 0; nj < 4; nj++) acc[mi][nj] = (f32x4){0.f,0.f,0.f,0.f};

  stage(0);
  for (int it = 0; it < 2; it++) {
    const int cur = it & 1;
    barrier_full();
    if (it == 0) stage(1);
    #pragma unroll
    for (int ks = 0; ks < 2; ks++) {
      const int cb = ((ks*4 + quad) ^ (m & 7)) << 3;
      bf16x8 af[2], wf[4];
      #pragma unroll
      for (int mi = 0; mi < 2; mi++)
        af[mi] = *(const bf16x8*)(&As[cur][(wv*32 + mi*16 + m) * 64 + cb]);
      #pragma unroll
      for (int nj = 0; nj < 4; nj++)
        wf[nj] = *(const bf16x8*)(&Ws[cur][(nj*16 + m) * 64 + cb]);
      #pragma unroll
      for (int mi = 0; mi < 2; mi++)
        #pragma unroll
        for (int nj = 0; nj < 4; nj++)
          acc[mi][nj] = __builtin_amdgcn_mfma_f32_16x16x32_bf16(af[mi], wf[nj], acc[mi][nj], 0, 0, 0);
    }
  }

  if (bn < 768) {
    #pragma unroll
    for (int mi = 0; mi < 2; mi++)
      #pragma unroll
      for (int nj = 0; nj < 4; nj++) {
        const int col = bn + nj*16 + m;
        #pragma unroll
        for (int r = 0; r < 4; r++) {
          const int row = bm + wv*32 + mi*16 + quad*4 + r;
          knope[(size_t)row * 768 + col] = __float2bfloat16(acc[mi][nj][r]);
        }
      }
  } else {
    barrier_full();
    short* TL = (short*)&As[0][0];          // [64 d][pitch 136]
    #pragma unroll
    for (int mi = 0; mi < 2; mi++)
      #pragma unroll
      for (int nj = 0; nj < 4; nj++) {
        const int d = nj*16 + m;
        #pragma unroll
        for (int r = 0; r < 4; r++) {
          const int tl = wv*32 + mi*16 + quad*4 + r;
          __hip_bfloat16 hv = __float2bfloat16(acc[mi][nj][r]);
          short sv; __builtin_memcpy(&sv, &hv, 2);
          TL[d*136 + tl] = sv;
        }
      }
    barrier_full();
    const int h = (bn - 768) >> 6;
    const int b = bm >> 11;
    const int t0 = bm & (T_ - 1);
    #pragma unroll
    for (int i = 0; i < 4; i++) {
      const int unit = i*256 + tid;        // 1024 units of 8 elems
      const int d = unit >> 4, tu = unit & 15;
      *(bf16x8*)(vt + ((size_t)(b*NH + h)*64 + d)*T_ + t0 + tu*8)
          = *(const bf16x8*)(TL + d*136 + tu*8);
    }
  }
}

// 2x2 wave-split flash attention, DIAGONAL PEEL, bare v_exp_f32 softmax.
// PV uses the guaranteed builtin mfma_f32_16x16x32_bf16 with ZERO-PADDED
// fragments (R16-verified structure: 172.35us, absmax 0.031). R19: every
// barrier force-drains all counters (barrier_full) to close the stale-LDS
// double-buffer race candidate. No inline asm anywhere.
__global__ __launch_bounds__(256, 4)
void attn_tile(const __hip_bfloat16* __restrict__ qb,
               const __hip_bfloat16* __restrict__ knope,
               const __hip_bfloat16* __restrict__ krope16,
               const __hip_bfloat16* __restrict__ vt16,
               __hip_bfloat16* __restrict__ aout)
{
  __shared__ __hip_bfloat16 SL[16384];  // K [2][64][64] @0/4096, V [2][64][64] @8192/12288
  const int tid = threadIdx.x;
  const int wv = tid >> 6, lane = tid & 63;
  const int m = lane & 15, quad = lane >> 4;
  const int wq = wv >> 1, wk = wv & 1;
  const int idx = (blockIdx.x + blockIdx.y) & 31;
  const int pj = idx & 7, pk = idx >> 3;
  const int qt = (pk == 0) ? pj : (pk == 1) ? (15 - pj) : (pk == 2) ? (16 + pj) : (31 - pj);
  const int bh = blockIdx.y;
  const int b = bh >> 4, h = bh & 15;
  const int nt = qt + 1;

  // Q for this wave's 32 q-rows (2 x 16-row tiles)
  bf16x8 q0[2], q1[2];
  #pragma unroll
  for (int t2 = 0; t2 < 2; t2++) {
    const __hip_bfloat16* qr = qb + ((size_t)bh*T_ + qt*64 + wq*32 + t2*16 + m)*64 + quad*8;
    q0[t2] = *(const bf16x8*)qr; q1[t2] = *(const bf16x8*)(qr + 32);
  }

  const __hip_bfloat16* pK[2]; size_t iK[2];
  const __hip_bfloat16* pV[2];
  #pragma unroll
  for (int i = 0; i < 2; i++) {
    const int slot = i*256 + tid;
    const int krow = slot >> 3;                 // 0..63: K row (key) / V row (d)
    const int kde = (slot & 7) ^ (krow & 7);
    if (kde < 6) { pK[i] = knope + (size_t)(b*T_ + krow)*768 + h*48 + kde*8; iK[i] = (size_t)64*768; }
    else         { pK[i] = krope16 + (size_t)(b*T_ + krow)*16 + (kde-6)*8;   iK[i] = (size_t)64*16; }
    pV[i] = vt16 + ((size_t)bh*64 + krow)*T_ + kde*8;
  }

  auto stage = [&](int buf){
    #pragma unroll
    for (int i = 0; i < 2; i++) {
      gload_lds16(pK[i], SL + buf*4096 + (i*256 + wv*64)*8);
      gload_lds16(pV[i], SL + 8192 + buf*4096 + (i*256 + wv*64)*8);
      pK[i] += iK[i]; pV[i] += 64;
    }
  };

  f32x4 o[2][4];
  #pragma unroll
  for (int t2 = 0; t2 < 2; t2++)
    #pragma unroll
    for (int vs = 0; vs < 4; vs++) o[t2][vs] = (f32x4){0.f,0.f,0.f,0.f};
  float lrun[2] = {0.f, 0.f};

  const int swk = quad ^ (m & 7);
  const int qh = quad >> 1, ql = quad & 1;
  stage(0);

  // ---- maskless main loop: kt = 0 .. nt-2 ----
  for (int kt = 0; kt < nt - 1; kt++) {
    const int cur = kt & 1;
    barrier_full();
    stage(cur ^ 1);
    const __hip_bfloat16* Kc = SL + cur*4096;
    const __hip_bfloat16* Vc = SL + 8192 + cur*4096;

    f32x4 s[2][2];
    __builtin_amdgcn_s_setprio(1);
    #pragma unroll
    for (int ks = 0; ks < 2; ks++) {
      const __hip_bfloat16* kr = Kc + (wk*32 + ks*16 + m)*64;
      const bf16x8 kf0 = *(const bf16x8*)(kr + swk*8);
      const bf16x8 kf1 = *(const bf16x8*)(kr + (swk^4)*8);
      #pragma unroll
      for (int t2 = 0; t2 < 2; t2++) {
        f32x4 z = (f32x4){0.f,0.f,0.f,0.f};
        z = __builtin_amdgcn_mfma_f32_16x16x32_bf16(kf0, q0[t2], z, 0, 0, 0);
        z = __builtin_amdgcn_mfma_f32_16x16x32_bf16(kf1, q1[t2], z, 0, 0, 0);
        s[t2][ks] = z;
      }
    }
    __builtin_amdgcn_s_setprio(0);

    bf16x8 u8[2][2];
    #pragma unroll
    for (int t2 = 0; t2 < 2; t2++)
      #pragma unroll
      for (int ks = 0; ks < 2; ks++) {
        float p0 = fexp2(s[t2][ks][0] - 48.0f), p1 = fexp2(s[t2][ks][1] - 48.0f);
        float p2 = fexp2(s[t2][ks][2] - 48.0f), p3 = fexp2(s[t2][ks][3] - 48.0f);
        lrun[t2] += (p0 + p1) + (p2 + p3);
        union { unsigned ui[4]; bf16x8 v; } uu;
        uu.ui[0] = pack_bf16(p0, p1);
        uu.ui[1] = pack_bf16(p2, p3);
        uu.ui[2] = 0; uu.ui[3] = 0;
        u8[t2][ks] = uu.v;
      }

    __builtin_amdgcn_s_setprio(1);
    #pragma unroll
    for (int vs = 0; vs < 4; vs++)
      #pragma unroll
      for (int ks = 0; ks < 2; ks++) {
        const bf16x4 vf = *(const bf16x4*)(Vc + (vs*16 + m)*64
                            + (((wk*4 + ks*2 + qh) ^ (m & 7)) << 3) + (ql << 2));
        union { bf16x4 h2[2]; bf16x8 v8; } av;
        av.h2[0] = vf; av.h2[1] = (bf16x4){0,0,0,0};
        #pragma unroll
        for (int t2 = 0; t2 < 2; t2++)
          o[t2][vs] = __builtin_amdgcn_mfma_f32_16x16x32_bf16(av.v8, u8[t2][ks], o[t2][vs], 0, 0, 0);
      }
    __builtin_amdgcn_s_setprio(0);
  }

  // ---- peeled diagonal tile: kt = qt (causal masking lives only here) ----
  {
    const int cur = (nt - 1) & 1;
    barrier_full();
    const __hip_bfloat16* Kc = SL + cur*4096;
    const __hip_bfloat16* Vc = SL + 8192 + cur*4096;

    f32x4 s[2][2];
    __builtin_amdgcn_s_setprio(1);
    #pragma unroll
    for (int ks = 0; ks < 2; ks++) {
      const int gk2 = 2*wk + ks;
      if (gk2 <= 2*wq + 1) {
        const __hip_bfloat16* kr = Kc + (wk*32 + ks*16 + m)*64;
        const bf16x8 kf0 = *(const bf16x8*)(kr + swk*8);
        const bf16x8 kf1 = *(const bf16x8*)(kr + (swk^4)*8);
        #pragma unroll
        for (int t2 = 0; t2 < 2; t2++) {
          if (gk2 <= 2*wq + t2) {
            f32x4 z = (f32x4){0.f,0.f,0.f,0.f};
            z = __builtin_amdgcn_mfma_f32_16x16x32_bf16(kf0, q0[t2], z, 0, 0, 0);
            z = __builtin_amdgcn_mfma_f32_16x16x32_bf16(kf1, q1[t2], z, 0, 0, 0);
            s[t2][ks] = z;
          } else {
            s[t2][ks] = (f32x4){-1e30f,-1e30f,-1e30f,-1e30f};
          }
        }
      } else {
        s[0][ks] = (f32x4){-1e30f,-1e30f,-1e30f,-1e30f};
        s[1][ks] = (f32x4){-1e30f,-1e30f,-1e30f,-1e30f};
      }
    }
    __builtin_amdgcn_s_setprio(0);

    #pragma unroll
    for (int ks = 0; ks < 2; ks++)
      #pragma unroll
      for (int t2 = 0; t2 < 2; t2++)
        if (2*wk + ks == 2*wq + t2) {            // diagonal 16-block: element mask
          #pragma unroll
          for (int r = 0; r < 4; r++)
            if (quad*4 + r > m) s[t2][ks][r] = -1e30f;
        }

    bf16x8 u8[2][2];
    #pragma unroll
    for (int t2 = 0; t2 < 2; t2++)
      #pragma unroll
      for (int ks = 0; ks < 2; ks++) {
        float p0 = fexp2(s[t2][ks][0] - 48.0f), p1 = fexp2(s[t2][ks][1] - 48.0f);
        float p2 = fexp2(s[t2][ks][2] - 48.0f), p3 = fexp2(s[t2][ks][3] - 48.0f);
        lrun[t2] += (p0 + p1) + (p2 + p3);
        union { unsigned ui[4]; bf16x8 v; } uu;
        uu.ui[0] = pack_bf16(p0, p1);
        uu.ui[1] = pack_bf16(p2, p3);
        uu.ui[2] = 0; uu.ui[3] = 0;
        u8[t2][ks] = uu.v;
      }

    __builtin_amdgcn_s_setprio(1);
    #pragma unroll
    for (int vs = 0; vs < 4; vs++)
      #pragma unroll
      for (int ks = 0; ks < 2; ks++) {
        const bf16x4 vf = *(const bf16x4*)(Vc + (vs*16 + m)*64
                            + (((wk*4 + ks*2 + qh) ^ (m & 7)) << 3) + (ql << 2));
        union { bf16x4 h2[2]; bf16x8 v8; } av;
        av.h2[0] = vf; av.h2[1] = (bf16x4){0,0,0,0};
        #pragma unroll
        for (int t2 = 0; t2 < 2; t2++)
          o[t2][vs] = __builtin_amdgcn_mfma_f32_16x16x32_bf16(av.v8, u8[t2][ks], o[t2][vs], 0, 0, 0);
      }
    __builtin_amdgcn_s_setprio(0);
  }

  // combine wk partners (partials over disjoint key sets sum exactly), store
  barrier_full();
  float* FB = (float*)SL;               // 4096 floats (reuses K region)
  float* LB = ((float*)SL) + 4096;      // 256 floats (start of V region)
  if (wk == 1) {
    #pragma unroll
    for (int t2 = 0; t2 < 2; t2++)
      #pragma unroll
      for (int vs = 0; vs < 4; vs++)
        #pragma unroll
        for (int r = 0; r < 4; r++)
          FB[wq*2048 + ((t2*4 + vs)*4 + r)*64 + lane] = o[t2][vs][r];
    LB[wq*128 + lane]      = lrun[0];
    LB[wq*128 + 64 + lane] = lrun[1];
  }
  barrier_full();
  if (wk == 0) {
    #pragma unroll
    for (int t2 = 0; t2 < 2; t2++)
      #pragma unroll
      for (int vs = 0; vs < 4; vs++)
        #pragma unroll
        for (int r = 0; r < 4; r++)
          o[t2][vs][r] += FB[wq*2048 + ((t2*4 + vs)*4 + r)*64 + lane];
    lrun[0] += LB[wq*128 + lane];
    lrun[1] += LB[wq*128 + 64 + lane];
    #pragma unroll
    for (int t2 = 0; t2 < 2; t2++) {
      float l = lrun[t2];
      l += __shfl_xor(l, 16, 64);
      l += __shfl_xor(l, 32, 64);
      const float inv = 1.0f / l;
      const size_t base = (size_t)(b*T_ + qt*64 + wq*32 + t2*16 + m) * 1024 + h*64 + quad*4;
      #pragma unroll
      for (int vs = 0; vs < 4; vs++) {
        union { unsigned ui[2]; bf16x4 v; } pkv;
        pkv.ui[0] = pack_bf16(o[t2][vs][0] * inv, o[t2][vs][1] * inv);
        pkv.ui[1] = pack_bf16(o[t2][vs][2] * inv, o[t2][vs][3] * inv);
        *(bf16x4*)(aout + base + vs*16) = pkv.v;
      }
    }
  }
}

extern "C" void kernel_launch(void* const* d_in, const int* in_sizes, int n_in,
                              void* d_out, int out_size, void* d_ws, size_t ws_size,
                              hipStream_t stream)
{
  const float* x    = (const float*)d_in[0];
  const float* cosp = (const float*)d_in[1];
  const float* sinp = (const float*)d_in[2];
  const float* Wq   = (const float*)d_in[3];
  const float* qw   = (const float*)d_in[4];
  const float* Wkva = (const float*)d_in[5];
  const float* kw   = (const float*)d_in[6];
  const float* Wkvb = (const float*)d_in[7];
  const float* Wo   = (const float*)d_in[8];
  float* out = (float*)d_out;

  float* kva = (float*)d_ws;                                  //   589,824 f
  __hip_bfloat16* xb16    = (__hip_bfloat16*)(kva + 589824);  // 4,194,304
  __hip_bfloat16* knope16 = xb16 + 4194304;                   // 3,145,728
  __hip_bfloat16* kvl16   = knope16 + 3145728;                //   524,288
  __hip_bfloat16* qb16    = kvl16 + 524288;                   // 4,194,304
  __hip_bfloat16* vt16    = qb16 + 4194304;                   // 4,194,304
  __hip_bfloat16* krope16 = vt16 + 4194304;                   //    65,536
  __hip_bfloat16* Wqb     = krope16 + 65536;                  // 1,048,576
  __hip_bfloat16* Wkvab   = Wqb + 1048576;                    //   147,456
  __hip_bfloat16* Wkvbb   = Wkvab + 147456;                   //   229,376
  __hip_bfloat16* Wob     = Wkvbb + 229376;                   // 1,048,576
  __hip_bfloat16* ab16    = Wob + 1048576;                    // 4,194,304

  const int M = B_ * T_;   // 4096

  cvt5<<<6512, 256, 0, stream>>>(x, Wq, Wkva, Wkvb, Wo, xb16, Wqb, Wkvab, Wkvbb, Wob);
  gemm_qkva<<<dim3(19, 32), 256, 0, stream>>>(xb16, Wqb, Wkvab, qw, cosp, sinp, qb16, kva);
  prep_kv<<<M, 128, 0, stream>>>(kva, kw, cosp, sinp, kvl16, krope16);
  gemm_kvb<<<dim3(28, 32), 256, 0, stream>>>(kvl16, Wkvbb, knope16, vt16);
  attn_tile<<<dim3(32, B_ * NH), 256, 0, stream>>>(qb16, knope16, krope16, vt16, ab16);
  gemm_bt64<float><<<dim3(16, 32), 256, 0, stream>>>(ab16, Wob, out, M, 1024, 1024);
}